// Round 16
// baseline (1080.464 us; speedup 1.0000x reference)
//
#include <hip/hip_runtime.h>

typedef unsigned short u16;
typedef unsigned int u32;
typedef __bf16 bf16x8 __attribute__((ext_vector_type(8)));
typedef float f32x4 __attribute__((ext_vector_type(4)));
typedef u16 u16x8 __attribute__((ext_vector_type(8)));
typedef u16 u16x4 __attribute__((ext_vector_type(4)));
typedef u32 u32x4 __attribute__((ext_vector_type(4)));

__device__ __forceinline__ u16 f2bf(float f){
  unsigned u = __float_as_uint(f);
  u += 0x7FFFu + ((u >> 16) & 1u);   // RNE
  return (u16)(u >> 16);
}
__device__ __forceinline__ float bf2f(u16 u){
  return __uint_as_float((u32)u << 16);
}
__device__ __forceinline__ u32 pack2bf(float a, float b){
  return (u32)f2bf(a) | ((u32)f2bf(b) << 16);
}
__device__ __forceinline__ void gload16(const void* g, void* l){
  __builtin_amdgcn_global_load_lds(
      (const __attribute__((address_space(1))) void*)g,
      (__attribute__((address_space(3))) void*)l, 16, 0, 0);
}

// ---------------- weight f32 [K][N] -> bf16 [drow0+N][K] (transposing convert) ----------------
__global__ __launch_bounds__(256) void conv_bf16_t(const float* __restrict__ src, u16* __restrict__ dst,
                                                   int K, int N, size_t dls, int drow0){
  __shared__ u16 s[64 * 68];
  size_t lo = (size_t)blockIdx.z * K * N;
  int n0 = blockIdx.x << 6, k0 = blockIdx.y << 6;
  int t = threadIdx.x;
#pragma unroll
  for (int p = 0; p < 4; ++p){
    int idx = p * 1024 + t * 4;
    int kl = idx >> 6, nl = idx & 63;
    f32x4 v = *(const f32x4*)(src + lo + (size_t)(k0 + kl) * N + n0 + nl);
#pragma unroll
    for (int j = 0; j < 4; ++j) s[(nl + j) * 68 + kl] = f2bf(v[j]);
  }
  __syncthreads();
  u16* db = dst + blockIdx.z * dls;
#pragma unroll
  for (int p = 0; p < 4; ++p){
    int idx = p * 1024 + t * 4;
    int nl = idx >> 6, kl = idx & 63;
    u16x4 o;
#pragma unroll
    for (int j = 0; j < 4; ++j) o[j] = s[nl * 68 + kl + j];
    *(u16x4*)(db + (size_t)(drow0 + n0 + nl) * K + k0 + kl) = o;
  }
}

// ---------------- plain f32 -> bf16 ----------------
__global__ __launch_bounds__(256) void conv_bf16(const float* __restrict__ src, u16* __restrict__ dst){
  size_t i = ((size_t)blockIdx.x * 256 + threadIdx.x) * 4;
  f32x4 v = *(const f32x4*)(src + i);
  u16x4 o;
#pragma unroll
  for (int j = 0; j < 4; ++j) o[j] = f2bf(v[j]);
  *(u16x4*)(dst + i) = o;
}

// ---------------- embedding + positional encoding (bf16 residual only) ----------------
__global__ __launch_bounds__(256) void embed_k(const int* __restrict__ data, const float* __restrict__ emb,
                                               u16* __restrict__ hbf){
  int idx = blockIdx.x * 256 + threadIdx.x;       // 0 .. 2M-1
  int r = idx >> 10, d = idx & 1023;              // r = i*4+b
  int i = r >> 2;
  int e = data[r];
  float val = emb[(size_t)e * 1024 + d] * 32.0f;  // sqrt(1024)
  float pos = (float)(511 - i);
  int t = d & 511;
  float freq = powf(10000.0f, -(float)t * (1.0f / 512.0f));
  float ang = pos * freq;
  val += (d < 512) ? sinf(ang) : cosf(ang);
  hbf[idx] = f2bf(val);
}

// ---------------- bf16 MFMA GEMM: C = A[M,K] @ Bt[N,K]^T (2-phase, proven) ----------------
template<int BM>
__global__ __launch_bounds__(256) void gemm_bt(
    const u16* __restrict__ A, const u16* __restrict__ Bt,
    const float* __restrict__ bias, float* __restrict__ C, u16* __restrict__ Cbf,
    u16* __restrict__ Cpart, int M, int N, int K, int kchunk, int relu,
    size_t zA, size_t zB, size_t zC,
    u16* __restrict__ VT, size_t zVT, int vcol0, int jdst0)
{
  constexpr int MFR = BM / 32;            // A frags per wave
  constexpr int ASZ = BM * 64, BSZ = 128 * 64;   // elements per buffer
  __shared__ __align__(16) u16 sA[2 * ASZ];
  __shared__ __align__(16) u16 sB[2 * BSZ];
  int tid = threadIdx.x, lane = tid & 63;
  int wr = (tid >> 7) & 1, wc = (tid >> 6) & 1;
  int m0 = blockIdx.y * BM, n0 = blockIdx.x << 7;
  int z = blockIdx.z;
  int kbeg = Cpart ? z * kchunk : 0;

  const u16* Ap = A + (size_t)z * zA;
  const u16* Bp = Bt + (size_t)z * zB;

  f32x4 acc[MFR][4];
#pragma unroll
  for (int i = 0; i < MFR; ++i)
#pragma unroll
    for (int j = 0; j < 4; ++j) acc[i][j] = (f32x4)(0.0f);

  int srow8 = tid >> 3;                   // 0..31
  int gslot8 = ((tid & 7) ^ (srow8 & 7)) << 3;
  const u16* Ab = Ap + (size_t)(m0 + srow8) * K + kbeg + gslot8;
  const u16* Bb = Bp + (size_t)(n0 + srow8) * K + kbeg + gslot8;
  const size_t rstep32 = (size_t)K << 5;  // 32 rows

  auto stage = [&](int buf, int k0){
#pragma unroll
    for (int p = 0; p < BM / 32; ++p)
      gload16(Ab + p * rstep32 + k0, (void*)&sA[buf * ASZ + p * 2048 + tid * 8]);
#pragma unroll
    for (int p = 0; p < 4; ++p)
      gload16(Bb + p * rstep32 + k0, (void*)&sB[buf * BSZ + p * 2048 + tid * 8]);
  };

  int r15 = lane & 15, g = lane >> 4;
  int s0 = g ^ (r15 & 7);
  const int o0 = s0 * 8, o1 = (s0 ^ 4) * 8;
  const int paBase = (wr * (BM / 2) + r15) * 64;
  const int pbBase = (wc * 64 + r15) * 64;

  int nk = kchunk >> 6;
  stage(0, 0);
  __syncthreads();
  for (int t = 0; t < nk; ++t){
    int cur = t & 1;
    if (t + 1 < nk) stage(cur ^ 1, (t + 1) << 6);
    const u16* pa = sA + cur * ASZ;
    const u16* pb = sB + cur * BSZ;
    bf16x8 af[MFR][2], bfv[4][2];
#pragma unroll
    for (int mi = 0; mi < MFR; ++mi){
      af[mi][0] = *(const bf16x8*)(pa + paBase + mi * 1024 + o0);
      af[mi][1] = *(const bf16x8*)(pa + paBase + mi * 1024 + o1);
    }
#pragma unroll
    for (int ni = 0; ni < 4; ++ni){
      bfv[ni][0] = *(const bf16x8*)(pb + pbBase + ni * 1024 + o0);
      bfv[ni][1] = *(const bf16x8*)(pb + pbBase + ni * 1024 + o1);
    }
#pragma unroll
    for (int kk = 0; kk < 2; ++kk)
#pragma unroll
      for (int mi = 0; mi < MFR; ++mi)
#pragma unroll
        for (int ni = 0; ni < 4; ++ni)
          acc[mi][ni] = __builtin_amdgcn_mfma_f32_16x16x32_bf16(af[mi][kk], bfv[ni][kk], acc[mi][ni], 0, 0, 0);
    __syncthreads();
  }

  int colf = lane & 15, rowf = (lane >> 4) << 2;
  bool vtile = (VT != nullptr) && (n0 >= vcol0);
  if (Cpart){
    u16* dst = Cpart + (size_t)z * M * N;
#pragma unroll
    for (int ni = 0; ni < 4; ++ni){
      int cg = n0 + (wc << 6) + ni * 16 + colf;
#pragma unroll
      for (int mi = 0; mi < MFR; ++mi){
        int rg = m0 + wr * (BM / 2) + mi * 16 + rowf;
#pragma unroll
        for (int r = 0; r < 4; ++r)
          dst[(size_t)(rg + r) * N + cg] = f2bf(acc[mi][ni][r]);
      }
    }
  } else {
    if (!(vtile && wc == 1)){
#pragma unroll
      for (int ni = 0; ni < 4; ++ni){
        int cg = n0 + (wc << 6) + ni * 16 + colf;
        float bv = bias ? bias[cg] : 0.0f;
#pragma unroll
        for (int mi = 0; mi < MFR; ++mi){
          int rg = m0 + wr * (BM / 2) + mi * 16 + rowf;
#pragma unroll
          for (int r = 0; r < 4; ++r){
            float val = acc[mi][ni][r] + bv;
            if (relu) val = fmaxf(val, 0.0f);
            size_t o = (size_t)(rg + r) * N + cg;
            if (C)   C[o]   = val;
            if (Cbf) (Cbf + (size_t)z * zC)[o] = f2bf(val);
          }
        }
      }
    }
    if (vtile){
      if (wc == 1){
#pragma unroll
        for (int ni = 0; ni < 4; ++ni)
#pragma unroll
          for (int mi = 0; mi < MFR; ++mi)
#pragma unroll
            for (int r = 0; r < 4; ++r)
              sA[(wr * (BM / 2) + mi * 16 + rowf + r) * 68 + ni * 16 + colf] = f2bf(acc[mi][ni][r]);
      }
      __syncthreads();
      int vb = tid >> 6, vd = tid & 63;
      int nh = (n0 - vcol0) >> 7;
      u16* dst = VT + (size_t)z * zVT + (((size_t)((vb << 4) + nh) << 6) + vd) * 1024 + jdst0 + (m0 >> 2);
      u16 tmp[BM / 4];
#pragma unroll
      for (int jj = 0; jj < BM / 4; ++jj) tmp[jj] = sA[((jj << 2) + vb) * 68 + vd];
#pragma unroll
      for (int c = 0; c < BM / 32; ++c)
        *(u16x8*)(dst + c * 8) = *(const u16x8*)(&tmp[c * 8]);
    }
  }
}

// ---------------- 8-phase 128x256 GEMM (T3+T4): 512 threads / 8 waves / 96KB LDS ----------------
// Per K-tile group: 4 phases {ds_read subtile -> s_barrier -> lgkmcnt(0) -> setprio(1) 8xMFMA
// setprio(0) -> s_barrier}; stage(u+1) issued at phase 0, drained by single vmcnt(0) at group end
// (covered by ~4 MFMA phases). Raw s_barrier (no vmcnt) between phases keeps loads in flight.
__global__ __launch_bounds__(512) void gemm8ph(
    const u16* __restrict__ A, const u16* __restrict__ Bt,
    const float* __restrict__ bias, u16* __restrict__ Cbf,
    int N, int K, int relu)
{
  __shared__ __align__(16) u16 sA[2][128 * 64];
  __shared__ __align__(16) u16 sB[2][256 * 64];
  int tid = threadIdx.x, lane = tid & 63, wid = tid >> 6;
  int wr = wid >> 2, wc = wid & 3;
  int m0 = blockIdx.y << 7, n0 = blockIdx.x << 8;

  f32x4 acc[4][4];
#pragma unroll
  for (int i = 0; i < 4; ++i)
#pragma unroll
    for (int j = 0; j < 4; ++j) acc[i][j] = (f32x4)(0.0f);

  int srow = tid >> 3;                    // 0..63
  int gslot = ((tid & 7) ^ (srow & 7)) << 3;
  const u16* Ab = A + (size_t)(m0 + srow) * K + gslot;
  const u16* Bb = Bt + (size_t)(n0 + srow) * K + gslot;
  const size_t r64 = (size_t)K << 6;      // 64 rows

  auto stage = [&](int buf, int kt){
    int k0 = kt << 6;
    gload16(Ab + k0,            (void*)&sA[buf][tid * 8]);
    gload16(Ab + r64 + k0,      (void*)&sA[buf][4096 + tid * 8]);
    gload16(Bb + k0,            (void*)&sB[buf][tid * 8]);
    gload16(Bb + r64 + k0,      (void*)&sB[buf][4096 + tid * 8]);
    gload16(Bb + 2 * r64 + k0,  (void*)&sB[buf][8192 + tid * 8]);
    gload16(Bb + 3 * r64 + k0,  (void*)&sB[buf][12288 + tid * 8]);
  };

  int r15 = lane & 15, g = lane >> 4;
  int s0 = g ^ (r15 & 7);
  const int o0 = s0 * 8, o1 = (s0 ^ 4) * 8;
  const int aRow = wr * 64 + r15;         // + mi*16
  const int bRow = wc * 64 + r15;         // + ni*16

  int nu = K >> 6;
  stage(0, 0);
  asm volatile("s_waitcnt vmcnt(0)" ::: "memory");
  __builtin_amdgcn_s_barrier();

  for (int u = 0; u < nu; ++u){
    int cb = u & 1;
    const u16* pa = &sA[cb][0];
    const u16* pb = &sB[cb][0];
    bf16x8 bf[4], af[2];
    // ---------- phase 0: prefetch next tile; B kk0 + A mi0,1 kk0 ----------
    if (u + 1 < nu) stage(cb ^ 1, u + 1);
#pragma unroll
    for (int ni = 0; ni < 4; ++ni) bf[ni] = *(const bf16x8*)(pb + (bRow + ni * 16) * 64 + o0);
    af[0] = *(const bf16x8*)(pa + (aRow + 0) * 64 + o0);
    af[1] = *(const bf16x8*)(pa + (aRow + 16) * 64 + o0);
    __builtin_amdgcn_s_barrier();
    asm volatile("s_waitcnt lgkmcnt(0)" ::: "memory");
    __builtin_amdgcn_sched_barrier(0);
    __builtin_amdgcn_s_setprio(1);
#pragma unroll
    for (int ni = 0; ni < 4; ++ni){
      acc[0][ni] = __builtin_amdgcn_mfma_f32_16x16x32_bf16(af[0], bf[ni], acc[0][ni], 0, 0, 0);
      acc[1][ni] = __builtin_amdgcn_mfma_f32_16x16x32_bf16(af[1], bf[ni], acc[1][ni], 0, 0, 0);
    }
    __builtin_amdgcn_s_setprio(0);
    __builtin_amdgcn_s_barrier();
    // ---------- phase 1: A mi2,3 kk0 (B kk0 reused from regs) ----------
    af[0] = *(const bf16x8*)(pa + (aRow + 32) * 64 + o0);
    af[1] = *(const bf16x8*)(pa + (aRow + 48) * 64 + o0);
    __builtin_amdgcn_s_barrier();
    asm volatile("s_waitcnt lgkmcnt(0)" ::: "memory");
    __builtin_amdgcn_sched_barrier(0);
    __builtin_amdgcn_s_setprio(1);
#pragma unroll
    for (int ni = 0; ni < 4; ++ni){
      acc[2][ni] = __builtin_amdgcn_mfma_f32_16x16x32_bf16(af[0], bf[ni], acc[2][ni], 0, 0, 0);
      acc[3][ni] = __builtin_amdgcn_mfma_f32_16x16x32_bf16(af[1], bf[ni], acc[3][ni], 0, 0, 0);
    }
    __builtin_amdgcn_s_setprio(0);
    __builtin_amdgcn_s_barrier();
    // ---------- phase 2: B kk1 + A mi0,1 kk1 ----------
#pragma unroll
    for (int ni = 0; ni < 4; ++ni) bf[ni] = *(const bf16x8*)(pb + (bRow + ni * 16) * 64 + o1);
    af[0] = *(const bf16x8*)(pa + (aRow + 0) * 64 + o1);
    af[1] = *(const bf16x8*)(pa + (aRow + 16) * 64 + o1);
    __builtin_amdgcn_s_barrier();
    asm volatile("s_waitcnt lgkmcnt(0)" ::: "memory");
    __builtin_amdgcn_sched_barrier(0);
    __builtin_amdgcn_s_setprio(1);
#pragma unroll
    for (int ni = 0; ni < 4; ++ni){
      acc[0][ni] = __builtin_amdgcn_mfma_f32_16x16x32_bf16(af[0], bf[ni], acc[0][ni], 0, 0, 0);
      acc[1][ni] = __builtin_amdgcn_mfma_f32_16x16x32_bf16(af[1], bf[ni], acc[1][ni], 0, 0, 0);
    }
    __builtin_amdgcn_s_setprio(0);
    __builtin_amdgcn_s_barrier();
    // ---------- phase 3: A mi2,3 kk1; group-end vmcnt(0) drain ----------
    af[0] = *(const bf16x8*)(pa + (aRow + 32) * 64 + o1);
    af[1] = *(const bf16x8*)(pa + (aRow + 48) * 64 + o1);
    __builtin_amdgcn_s_barrier();
    asm volatile("s_waitcnt lgkmcnt(0)" ::: "memory");
    __builtin_amdgcn_sched_barrier(0);
    __builtin_amdgcn_s_setprio(1);
#pragma unroll
    for (int ni = 0; ni < 4; ++ni){
      acc[2][ni] = __builtin_amdgcn_mfma_f32_16x16x32_bf16(af[0], bf[ni], acc[2][ni], 0, 0, 0);
      acc[3][ni] = __builtin_amdgcn_mfma_f32_16x16x32_bf16(af[1], bf[ni], acc[3][ni], 0, 0, 0);
    }
    __builtin_amdgcn_s_setprio(0);
    asm volatile("s_waitcnt vmcnt(0)" ::: "memory");
    __builtin_amdgcn_s_barrier();
  }

  int colf = lane & 15, rowf = (lane >> 4) << 2;
#pragma unroll
  for (int ni = 0; ni < 4; ++ni){
    int cg = n0 + wc * 64 + ni * 16 + colf;
    float bv = bias ? bias[cg] : 0.0f;
#pragma unroll
    for (int mi = 0; mi < 4; ++mi){
      int rg = m0 + wr * 64 + mi * 16 + rowf;
#pragma unroll
      for (int r = 0; r < 4; ++r){
        float val = acc[mi][ni][r] + bv;
        if (relu) val = fmaxf(val, 0.0f);
        Cbf[(size_t)(rg + r) * N + cg] = f2bf(val);
      }
    }
  }
}

// ---------------- MFMA flash attention: pair-wise 4-buffer loop + setprio ----------------
__global__ __launch_bounds__(256) void attn_mfma(
    const u16* __restrict__ qkv, const u16* __restrict__ kvm,
    const u16* __restrict__ vtbf, u16* __restrict__ attnbf)
{
  __shared__ __align__(16) u16 sK[4][64 * 64];
  __shared__ __align__(16) u16 sV[4][64 * 64];
  int tid = threadIdx.x, lane = tid & 63, wid = tid >> 6;
  int g = lane >> 4, t = lane & 15;
  int qt = blockIdx.x, bnp = blockIdx.y;
  int b = bnp >> 4, n = bnp & 15;
  int i0 = qt * 64 + wid * 16;
  int i = i0 + t;

  union Cvt { u32x4 u; bf16x8 v; };

  bf16x8 qfrag[2];
#pragma unroll
  for (int ks = 0; ks < 2; ++ks)
    qfrag[ks] = *(const bf16x8*)(qkv + (size_t)(i * 4 + b) * 3072 + n * 64 + ks * 32 + g * 8);

  f32x4 oacc[4];
#pragma unroll
  for (int df = 0; df < 4; ++df) oacc[df] = (f32x4)(0.0f);
  float mrun = -1e30f, lrun = 0.0f;

  const u16* kbm = kvm + n * 128;
  const u16* kbh = qkv + 1024 + n * 128;
  const u16* vb2 = vtbf + ((size_t)bnp << 16);   // rows d, stride 1024

  int srow = tid >> 3;                    // 0..31
  int gsl = ((tid & 7) ^ (srow & 7)) << 3;

  auto stageKV = [&](int buf, int kt){
    int j0 = kt << 6;
    const u16* kb = (kt < 8) ? kbm : kbh;
    size_t kst = (kt < 8) ? 2048 : 3072;
    int joff = (kt < 8) ? 0 : 512;
#pragma unroll
    for (int p = 0; p < 2; ++p){
      int jl = srow + p * 32;
      gload16(kb + (size_t)((j0 + jl - joff) * 4 + b) * kst + gsl, (void*)&sK[buf][p * 2048 + tid * 8]);
    }
#pragma unroll
    for (int p = 0; p < 2; ++p){
      int dl = srow + p * 32;
      gload16(vb2 + ((size_t)dl << 10) + j0 + gsl, (void*)&sV[buf][p * 2048 + tid * 8]);
    }
  };

  auto compute = [&](int cur, int kt){
    int j0 = kt << 6;
    f32x4 sacc[4];
#pragma unroll
    for (int jf = 0; jf < 4; ++jf) sacc[jf] = (f32x4)(0.0f);
    __builtin_amdgcn_s_setprio(1);
#pragma unroll
    for (int ks = 0; ks < 2; ++ks){
      int sl = ((ks * 4 + g) ^ (t & 7)) * 8;
#pragma unroll
      for (int jf = 0; jf < 4; ++jf){
        bf16x8 kf = *(const bf16x8*)(&sK[cur][(jf * 16 + t) * 64 + sl]);
        sacc[jf] = __builtin_amdgcn_mfma_f32_16x16x32_bf16(kf, qfrag[ks], sacc[jf], 0, 0, 0);
      }
    }
    __builtin_amdgcn_s_setprio(0);
    bool part = (j0 + 63 > i0 + 512);
    float ps[4][4];
    float tmax = -1e30f;
#pragma unroll
    for (int jf = 0; jf < 4; ++jf)
#pragma unroll
      for (int r = 0; r < 4; ++r){
        float s = sacc[jf][r] * 0.125f;
        if (part && (j0 + jf * 16 + g * 4 + r > i + 512)) s = -1e30f;
        ps[jf][r] = s;
        tmax = fmaxf(tmax, s);
      }
    tmax = fmaxf(tmax, __shfl_xor(tmax, 16));
    tmax = fmaxf(tmax, __shfl_xor(tmax, 32));
    float mnew = fmaxf(mrun, tmax);
    float sc = __expf(mrun - mnew);
    mrun = mnew;
    lrun *= sc;
    u32 pk0[2], pk1[2], pk2[2], pk3[2];
    {
      float e0, e1, e2, e3;
#define DO_JF(PK, JF) \
      e0 = __expf(ps[JF][0] - mnew); e1 = __expf(ps[JF][1] - mnew); \
      e2 = __expf(ps[JF][2] - mnew); e3 = __expf(ps[JF][3] - mnew); \
      lrun += (e0 + e1) + (e2 + e3); \
      PK[0] = pack2bf(e0, e1); PK[1] = pack2bf(e2, e3);
      DO_JF(pk0, 0) DO_JF(pk1, 1) DO_JF(pk2, 2) DO_JF(pk3, 3)
#undef DO_JF
    }
#pragma unroll
    for (int df = 0; df < 4; ++df)
#pragma unroll
      for (int r = 0; r < 4; ++r) oacc[df][r] *= sc;

    int srcA = t + 16 * ((2 * g) & 3);
    int srcB = t + 16 * ((2 * g + 1) & 3);
    bool ghi = (g >= 2);
#pragma unroll
    for (int ks = 0; ks < 2; ++ks){
      u32 w0a, w1a, w2a, w3a, w0b, w1b, w2b, w3b;
      if (ks == 0){
        w0a = __shfl((int)pk0[0], srcA); w1a = __shfl((int)pk0[1], srcA);
        w2a = __shfl((int)pk0[0], srcB); w3a = __shfl((int)pk0[1], srcB);
        w0b = __shfl((int)pk1[0], srcA); w1b = __shfl((int)pk1[1], srcA);
        w2b = __shfl((int)pk1[0], srcB); w3b = __shfl((int)pk1[1], srcB);
      } else {
        w0a = __shfl((int)pk2[0], srcA); w1a = __shfl((int)pk2[1], srcA);
        w2a = __shfl((int)pk2[0], srcB); w3a = __shfl((int)pk2[1], srcB);
        w0b = __shfl((int)pk3[0], srcA); w1b = __shfl((int)pk3[1], srcA);
        w2b = __shfl((int)pk3[0], srcB); w3b = __shfl((int)pk3[1], srcB);
      }
      Cvt c;
      c.u[0] = ghi ? w0b : w0a;
      c.u[1] = ghi ? w1b : w1a;
      c.u[2] = ghi ? w2b : w2a;
      c.u[3] = ghi ? w3b : w3a;
      bf16x8 pf = c.v;
      int sl = ((ks * 4 + g) ^ (t & 7)) * 8;
      __builtin_amdgcn_s_setprio(1);
#pragma unroll
      for (int df = 0; df < 4; ++df){
        bf16x8 vf = *(const bf16x8*)(&sV[cur][(df * 16 + t) * 64 + sl]);
        oacc[df] = __builtin_amdgcn_mfma_f32_16x16x32_bf16(vf, pf, oacc[df], 0, 0, 0);
      }
      __builtin_amdgcn_s_setprio(0);
    }
  };

  int kt1 = qt + 9;
  stageKV(0, 0);
  stageKV(1, 1);
  __syncthreads();
  for (int kt = 0; kt < kt1; kt += 2){
    if (kt + 2 < kt1) stageKV((kt + 2) & 3, kt + 2);
    if (kt + 3 < kt1) stageKV((kt + 3) & 3, kt + 3);
    compute(kt & 3, kt);
    if (kt + 1 < kt1) compute((kt + 1) & 3, kt + 1);
    __syncthreads();
  }
  lrun += __shfl_xor(lrun, 16);
  lrun += __shfl_xor(lrun, 32);
  float inv = 1.0f / lrun;

  u16* orow = attnbf + ((size_t)(i * 4 + b) << 10) + n * 64;
#pragma unroll
  for (int df = 0; df < 4; ++df){
#pragma unroll
    for (int h = 0; h < 2; ++h){
      *(u32*)(orow + df * 16 + g * 4 + 2 * h) = pack2bf(oacc[df][2 * h] * inv, oacc[df][2 * h + 1] * inv);
    }
  }
}

// ---------------- bf16 residual + (bf16 split-K partial sum) + bias + layernorm ----------------
__global__ __launch_bounds__(256) void ln_k(const u16* __restrict__ resbf, const u16* __restrict__ parts,
                                            size_t pstride, int np, const float* __restrict__ bias,
                                            const float* __restrict__ g, const float* __restrict__ bta,
                                            u16* __restrict__ hbf, float* __restrict__ fout)
{
  int row = blockIdx.x, tid = threadIdx.x;
  int d0 = tid << 2;
  size_t ro = (size_t)row << 10;
  u16x4 rv = *(const u16x4*)(resbf + ro + d0);
  f32x4 v;
#pragma unroll
  for (int j = 0; j < 4; ++j) v[j] = bf2f(rv[j]);
  if (bias){
    f32x4 bv = *(const f32x4*)(bias + d0);
#pragma unroll
    for (int j = 0; j < 4; ++j) v[j] += bv[j];
  }
  for (int p = 0; p < np; ++p){
    u16x4 pv = *(const u16x4*)(parts + p * pstride + ro + d0);
#pragma unroll
    for (int j = 0; j < 4; ++j) v[j] += bf2f(pv[j]);
  }
  float s = (v[0] + v[1]) + (v[2] + v[3]);
  float s2 = (v[0] * v[0] + v[1] * v[1]) + (v[2] * v[2] + v[3] * v[3]);
#pragma unroll
  for (int off = 32; off; off >>= 1){ s += __shfl_xor(s, off); s2 += __shfl_xor(s2, off); }
  __shared__ float ps[8];
  int wid = tid >> 6, lane = tid & 63;
  if (lane == 0){ ps[wid] = s; ps[wid + 4] = s2; }
  __syncthreads();
  s  = ps[0] + ps[1] + ps[2] + ps[3];
  s2 = ps[4] + ps[5] + ps[6] + ps[7];
  float mu = s * 0.0009765625f;
  float var = s2 * 0.0009765625f - mu * mu;
  float rstd = rsqrtf(var + 1e-5f);
  f32x4 gv = *(const f32x4*)(g + d0);
  f32x4 bt = *(const f32x4*)(bta + d0);
  f32x4 fo;
  u16x4 hb;
#pragma unroll
  for (int j = 0; j < 4; ++j){
    float tv = (v[j] - mu) * rstd * gv[j] + bt[j];
    fo[j] = tv; hb[j] = f2bf(tv);
  }
  *(u16x4*)(hbf + ro + d0) = hb;
  if (fout) *(f32x4*)(fout + ro + d0) = fo;
}

extern "C" void kernel_launch(void* const* d_in, const int* in_sizes, int n_in,
                              void* d_out, int out_size, void* d_ws, size_t ws_size,
                              hipStream_t stream)
{
  const int*   data = (const int*)  d_in[0];
  const float* mems = (const float*)d_in[1];
  const float* emb  = (const float*)d_in[2];
  const float* Wq   = (const float*)d_in[3];
  const float* Wkv  = (const float*)d_in[4];
  const float* Wo   = (const float*)d_in[5];
  const float* ln1g = (const float*)d_in[6];
  const float* ln1b = (const float*)d_in[7];
  const float* W1   = (const float*)d_in[8];
  const float* b1   = (const float*)d_in[9];
  const float* W2   = (const float*)d_in[10];
  const float* b2   = (const float*)d_in[11];
  const float* ln2g = (const float*)d_in[12];
  const float* ln2b = (const float*)d_in[13];
  float* out = (float*)d_out;

  char* ws = (char*)d_ws;
  size_t off = 0;
  auto alloc = [&](size_t bytes) -> char* {
    char* p = ws + off;
    off = (off + bytes + 255) & ~(size_t)255;
    return p;
  };

  u16*   wqkv_bf = (u16*) alloc((size_t)6 * 3072 * 1024 * 2);
  u16*   wo_bf   = (u16*) alloc((size_t)6 * 1024 * 1024 * 2);
  u16*   w1_bf   = (u16*) alloc((size_t)6 * 4096 * 1024 * 2);
  u16*   w2_bf   = (u16*) alloc((size_t)6 * 1024 * 4096 * 2);
  u16*   memsbf  = (u16*) alloc((size_t)6 * 2048 * 1024 * 2);
  u16*   kvmem   = (u16*) alloc((size_t)6 * 2048 * 2048 * 2);
  u16*   vtbf    = (u16*) alloc((size_t)6 * 64 * 64 * 1024 * 2);
  u16*   hbf     = (u16*) alloc((size_t)2048 * 1024 * 2);
  u16*   qkv     = (u16*) alloc((size_t)2048 * 3072 * 2);
  u16*   attnbf  = (u16*) alloc((size_t)2048 * 1024 * 2);
  u16*   f1bf    = (u16*) alloc((size_t)2048 * 4096 * 2);
  u16*   pbf     = (u16*) alloc((size_t)4 * 2048 * 1024 * 2);
  const size_t PS = (size_t)2048 * 1024;
  const size_t VTL = (size_t)64 * 64 * 1024;

  // ---- layer-independent preamble ----
  conv_bf16_t<<<dim3(16, 16, 6), 256, 0, stream>>>(Wq,  wqkv_bf, 1024, 1024, (size_t)3072 * 1024, 0);
  conv_bf16_t<<<dim3(32, 16, 6), 256, 0, stream>>>(Wkv, wqkv_bf, 1024, 2048, (size_t)3072 * 1024, 1024);
  conv_bf16_t<<<dim3(16, 16, 6), 256, 0, stream>>>(Wo,  wo_bf,   1024, 1024, (size_t)1024 * 1024, 0);
  conv_bf16_t<<<dim3(64, 16, 6), 256, 0, stream>>>(W1,  w1_bf,   1024, 4096, (size_t)4096 * 1024, 0);
  conv_bf16_t<<<dim3(16, 64, 6), 256, 0, stream>>>(W2,  w2_bf,   4096, 1024, (size_t)4096 * 1024, 0);
  conv_bf16<<<12288, 256, 0, stream>>>(mems, memsbf);
  embed_k<<<8192, 256, 0, stream>>>(data, emb, hbf);
  // batched mems-KV GEMM (BM=128) with fused V-transpose
  gemm_bt<128><<<dim3(16, 16, 6), 256, 0, stream>>>(memsbf, wqkv_bf + (size_t)1024 * 1024, nullptr,
      nullptr, kvmem, nullptr, 2048, 2048, 1024, 1024, 0,
      (size_t)2048 * 1024, (size_t)3072 * 1024, (size_t)2048 * 2048,
      vtbf, VTL, 0, 0);

  for (int l = 0; l < 6; ++l){
    u16* kvm_l = kvmem + (size_t)l * 2048 * 2048;
    u16* vt_l  = vtbf + (size_t)l * VTL;
    gemm_bt<64><<<dim3(24, 32), 256, 0, stream>>>(hbf, wqkv_bf + (size_t)l * 3072 * 1024, nullptr,
        nullptr, qkv, nullptr, 2048, 3072, 1024, 1024, 0, 0, 0, 0,
        vt_l, 0, 1024, 512);
    attn_mfma<<<dim3(8, 64), 256, 0, stream>>>(qkv, kvm_l, vt_l, attnbf);
    gemm_bt<64><<<dim3(8, 32, 2), 256, 0, stream>>>(attnbf, wo_bf + (size_t)l * 1024 * 1024, nullptr,
        nullptr, nullptr, pbf, 2048, 1024, 1024, 512, 0, 0, 0, 0,
        nullptr, 0, 0, 0);
    ln_k<<<2048, 256, 0, stream>>>(hbf, pbf, PS, 2, nullptr, ln1g + l * 1024, ln1b + l * 1024, hbf, nullptr);
    // W1 + bias + relu: 8-phase 128x256 kernel, grid 16x16 = 256 blocks = 1/CU
    gemm8ph<<<dim3(16, 16), 512, 0, stream>>>(hbf, w1_bf + (size_t)l * 4096 * 1024,
        b1 + (size_t)l * 4096, f1bf, 4096, 1024, 1);
    gemm_bt<128><<<dim3(8, 16, 4), 256, 0, stream>>>(f1bf, w2_bf + (size_t)l * 4096 * 1024, nullptr,
        nullptr, nullptr, pbf, 2048, 1024, 4096, 1024, 0, 0, 0, 0,
        nullptr, 0, 0, 0);
    ln_k<<<2048, 256, 0, stream>>>(hbf, pbf, PS, 4, b2 + l * 1024, ln2g + l * 1024, ln2b + l * 1024,
                                   hbf, (l == 5) ? out : nullptr);
  }
}

// Round 17
// 986.081 us; speedup vs baseline: 1.0957x; 1.0957x over previous
//
#include <hip/hip_runtime.h>

typedef unsigned short u16;
typedef unsigned int u32;
typedef __bf16 bf16x8 __attribute__((ext_vector_type(8)));
typedef float f32x4 __attribute__((ext_vector_type(4)));
typedef u16 u16x8 __attribute__((ext_vector_type(8)));
typedef u16 u16x4 __attribute__((ext_vector_type(4)));
typedef u32 u32x4 __attribute__((ext_vector_type(4)));

__device__ __forceinline__ u16 f2bf(float f){
  unsigned u = __float_as_uint(f);
  u += 0x7FFFu + ((u >> 16) & 1u);   // RNE
  return (u16)(u >> 16);
}
__device__ __forceinline__ float bf2f(u16 u){
  return __uint_as_float((u32)u << 16);
}
__device__ __forceinline__ u32 pack2bf(float a, float b){
  return (u32)f2bf(a) | ((u32)f2bf(b) << 16);
}
__device__ __forceinline__ void gload16(const void* g, void* l){
  __builtin_amdgcn_global_load_lds(
      (const __attribute__((address_space(1))) void*)g,
      (__attribute__((address_space(3))) void*)l, 16, 0, 0);
}

// ---------------- weight f32 [K][N] -> bf16 [drow0+N][K] (transposing convert) ----------------
__global__ __launch_bounds__(256) void conv_bf16_t(const float* __restrict__ src, u16* __restrict__ dst,
                                                   int K, int N, size_t dls, int drow0){
  __shared__ u16 s[64 * 68];
  size_t lo = (size_t)blockIdx.z * K * N;
  int n0 = blockIdx.x << 6, k0 = blockIdx.y << 6;
  int t = threadIdx.x;
#pragma unroll
  for (int p = 0; p < 4; ++p){
    int idx = p * 1024 + t * 4;
    int kl = idx >> 6, nl = idx & 63;
    f32x4 v = *(const f32x4*)(src + lo + (size_t)(k0 + kl) * N + n0 + nl);
#pragma unroll
    for (int j = 0; j < 4; ++j) s[(nl + j) * 68 + kl] = f2bf(v[j]);
  }
  __syncthreads();
  u16* db = dst + blockIdx.z * dls;
#pragma unroll
  for (int p = 0; p < 4; ++p){
    int idx = p * 1024 + t * 4;
    int nl = idx >> 6, kl = idx & 63;
    u16x4 o;
#pragma unroll
    for (int j = 0; j < 4; ++j) o[j] = s[nl * 68 + kl + j];
    *(u16x4*)(db + (size_t)(drow0 + n0 + nl) * K + k0 + kl) = o;
  }
}

// ---------------- plain f32 -> bf16 ----------------
__global__ __launch_bounds__(256) void conv_bf16(const float* __restrict__ src, u16* __restrict__ dst){
  size_t i = ((size_t)blockIdx.x * 256 + threadIdx.x) * 4;
  f32x4 v = *(const f32x4*)(src + i);
  u16x4 o;
#pragma unroll
  for (int j = 0; j < 4; ++j) o[j] = f2bf(v[j]);
  *(u16x4*)(dst + i) = o;
}

// ---------------- embedding + positional encoding (bf16 residual only) ----------------
__global__ __launch_bounds__(256) void embed_k(const int* __restrict__ data, const float* __restrict__ emb,
                                               u16* __restrict__ hbf){
  int idx = blockIdx.x * 256 + threadIdx.x;       // 0 .. 2M-1
  int r = idx >> 10, d = idx & 1023;              // r = i*4+b
  int i = r >> 2;
  int e = data[r];
  float val = emb[(size_t)e * 1024 + d] * 32.0f;  // sqrt(1024)
  float pos = (float)(511 - i);
  int t = d & 511;
  float freq = powf(10000.0f, -(float)t * (1.0f / 512.0f));
  float ang = pos * freq;
  val += (d < 512) ? sinf(ang) : cosf(ang);
  hbf[idx] = f2bf(val);
}

// ---------------- bf16 MFMA GEMM: C = A[M,K] @ Bt[N,K]^T (2-phase, proven) ----------------
// BK=64, 2-buffer schedule, row&7 slot swizzle, fused V-transpose epilogue, T1 XCD swizzle.
// Requires gridDim.x*gridDim.y*gridDim.z % 8 == 0 (all call sites satisfy).
template<int BM>
__global__ __launch_bounds__(256) void gemm_bt(
    const u16* __restrict__ A, const u16* __restrict__ Bt,
    const float* __restrict__ bias, float* __restrict__ C, u16* __restrict__ Cbf,
    u16* __restrict__ Cpart, int M, int N, int K, int kchunk, int relu,
    size_t zA, size_t zB, size_t zC,
    u16* __restrict__ VT, size_t zVT, int vcol0, int jdst0)
{
  constexpr int MFR = BM / 32;            // A frags per wave
  constexpr int ASZ = BM * 64, BSZ = 128 * 64;   // elements per buffer
  __shared__ __align__(16) u16 sA[2 * ASZ];
  __shared__ __align__(16) u16 sB[2 * BSZ];
  int tid = threadIdx.x, lane = tid & 63;
  int wr = (tid >> 7) & 1, wc = (tid >> 6) & 1;

  // T1: bijective XCD swizzle — XCD k handles a contiguous chunk of logical tiles
  u32 gx = gridDim.x, gy = gridDim.y;
  u32 flat = blockIdx.x + gx * (blockIdx.y + gy * blockIdx.z);
  u32 chunk = (gx * gy * gridDim.z) >> 3;
  u32 swz = (flat & 7) * chunk + (flat >> 3);
  u32 bx = swz % gx, rest = swz / gx;
  u32 by = rest % gy, bz = rest / gy;

  int m0 = by * BM, n0 = bx << 7;
  int z = bz;
  int kbeg = Cpart ? z * kchunk : 0;

  const u16* Ap = A + (size_t)z * zA;
  const u16* Bp = Bt + (size_t)z * zB;

  f32x4 acc[MFR][4];
#pragma unroll
  for (int i = 0; i < MFR; ++i)
#pragma unroll
    for (int j = 0; j < 4; ++j) acc[i][j] = (f32x4)(0.0f);

  int srow8 = tid >> 3;                   // 0..31
  int gslot8 = ((tid & 7) ^ (srow8 & 7)) << 3;
  const u16* Ab = Ap + (size_t)(m0 + srow8) * K + kbeg + gslot8;
  const u16* Bb = Bp + (size_t)(n0 + srow8) * K + kbeg + gslot8;
  const size_t rstep32 = (size_t)K << 5;  // 32 rows

  auto stage = [&](int buf, int k0){
#pragma unroll
    for (int p = 0; p < BM / 32; ++p)
      gload16(Ab + p * rstep32 + k0, (void*)&sA[buf * ASZ + p * 2048 + tid * 8]);
#pragma unroll
    for (int p = 0; p < 4; ++p)
      gload16(Bb + p * rstep32 + k0, (void*)&sB[buf * BSZ + p * 2048 + tid * 8]);
  };

  int r15 = lane & 15, g = lane >> 4;
  int s0 = g ^ (r15 & 7);
  const int o0 = s0 * 8, o1 = (s0 ^ 4) * 8;
  const int paBase = (wr * (BM / 2) + r15) * 64;
  const int pbBase = (wc * 64 + r15) * 64;

  int nk = kchunk >> 6;
  stage(0, 0);
  __syncthreads();
  for (int t = 0; t < nk; ++t){
    int cur = t & 1;
    if (t + 1 < nk) stage(cur ^ 1, (t + 1) << 6);
    const u16* pa = sA + cur * ASZ;
    const u16* pb = sB + cur * BSZ;
    bf16x8 af[MFR][2], bfv[4][2];
#pragma unroll
    for (int mi = 0; mi < MFR; ++mi){
      af[mi][0] = *(const bf16x8*)(pa + paBase + mi * 1024 + o0);
      af[mi][1] = *(const bf16x8*)(pa + paBase + mi * 1024 + o1);
    }
#pragma unroll
    for (int ni = 0; ni < 4; ++ni){
      bfv[ni][0] = *(const bf16x8*)(pb + pbBase + ni * 1024 + o0);
      bfv[ni][1] = *(const bf16x8*)(pb + pbBase + ni * 1024 + o1);
    }
#pragma unroll
    for (int kk = 0; kk < 2; ++kk)
#pragma unroll
      for (int mi = 0; mi < MFR; ++mi)
#pragma unroll
        for (int ni = 0; ni < 4; ++ni)
          acc[mi][ni] = __builtin_amdgcn_mfma_f32_16x16x32_bf16(af[mi][kk], bfv[ni][kk], acc[mi][ni], 0, 0, 0);
    __syncthreads();
  }

  int colf = lane & 15, rowf = (lane >> 4) << 2;
  bool vtile = (VT != nullptr) && (n0 >= vcol0);
  if (Cpart){
    u16* dst = Cpart + (size_t)z * M * N;
#pragma unroll
    for (int ni = 0; ni < 4; ++ni){
      int cg = n0 + (wc << 6) + ni * 16 + colf;
#pragma unroll
      for (int mi = 0; mi < MFR; ++mi){
        int rg = m0 + wr * (BM / 2) + mi * 16 + rowf;
#pragma unroll
        for (int r = 0; r < 4; ++r)
          dst[(size_t)(rg + r) * N + cg] = f2bf(acc[mi][ni][r]);
      }
    }
  } else {
    if (!(vtile && wc == 1)){
#pragma unroll
      for (int ni = 0; ni < 4; ++ni){
        int cg = n0 + (wc << 6) + ni * 16 + colf;
        float bv = bias ? bias[cg] : 0.0f;
#pragma unroll
        for (int mi = 0; mi < MFR; ++mi){
          int rg = m0 + wr * (BM / 2) + mi * 16 + rowf;
#pragma unroll
          for (int r = 0; r < 4; ++r){
            float val = acc[mi][ni][r] + bv;
            if (relu) val = fmaxf(val, 0.0f);
            size_t o = (size_t)(rg + r) * N + cg;
            if (C)   C[o]   = val;
            if (Cbf) (Cbf + (size_t)z * zC)[o] = f2bf(val);
          }
        }
      }
    }
    if (vtile){
      if (wc == 1){
#pragma unroll
        for (int ni = 0; ni < 4; ++ni)
#pragma unroll
          for (int mi = 0; mi < MFR; ++mi)
#pragma unroll
            for (int r = 0; r < 4; ++r)
              sA[(wr * (BM / 2) + mi * 16 + rowf + r) * 68 + ni * 16 + colf] = f2bf(acc[mi][ni][r]);
      }
      __syncthreads();
      int vb = tid >> 6, vd = tid & 63;
      int nh = (n0 - vcol0) >> 7;
      u16* dst = VT + (size_t)z * zVT + (((size_t)((vb << 4) + nh) << 6) + vd) * 1024 + jdst0 + (m0 >> 2);
      u16 tmp[BM / 4];
#pragma unroll
      for (int jj = 0; jj < BM / 4; ++jj) tmp[jj] = sA[((jj << 2) + vb) * 68 + vd];
#pragma unroll
      for (int c = 0; c < BM / 32; ++c)
        *(u16x8*)(dst + c * 8) = *(const u16x8*)(&tmp[c * 8]);
    }
  }
}

// ---------------- MFMA flash attention: pair-wise 4-buffer loop + setprio + XCD swizzle ----------------
__global__ __launch_bounds__(256) void attn_mfma(
    const u16* __restrict__ qkv, const u16* __restrict__ kvm,
    const u16* __restrict__ vtbf, u16* __restrict__ attnbf)
{
  __shared__ __align__(16) u16 sK[4][64 * 64];
  __shared__ __align__(16) u16 sV[4][64 * 64];
  int tid = threadIdx.x, lane = tid & 63, wid = tid >> 6;
  int g = lane >> 4, t = lane & 15;

  // T1: group all 8 qt-blocks of a (b,n) on one XCD for K/V L2 reuse (512 blocks, chunk=64)
  u32 flat = blockIdx.x + (blockIdx.y << 3);
  u32 swz = (flat & 7) * 64 + (flat >> 3);
  int qt = swz & 7, bnp = swz >> 3;

  int b = bnp >> 4, n = bnp & 15;
  int i0 = qt * 64 + wid * 16;
  int i = i0 + t;

  union Cvt { u32x4 u; bf16x8 v; };

  bf16x8 qfrag[2];
#pragma unroll
  for (int ks = 0; ks < 2; ++ks)
    qfrag[ks] = *(const bf16x8*)(qkv + (size_t)(i * 4 + b) * 3072 + n * 64 + ks * 32 + g * 8);

  f32x4 oacc[4];
#pragma unroll
  for (int df = 0; df < 4; ++df) oacc[df] = (f32x4)(0.0f);
  float mrun = -1e30f, lrun = 0.0f;

  const u16* kbm = kvm + n * 128;
  const u16* kbh = qkv + 1024 + n * 128;
  const u16* vb2 = vtbf + ((size_t)bnp << 16);   // rows d, stride 1024

  int srow = tid >> 3;                    // 0..31
  int gsl = ((tid & 7) ^ (srow & 7)) << 3;

  auto stageKV = [&](int buf, int kt){
    int j0 = kt << 6;
    const u16* kb = (kt < 8) ? kbm : kbh;
    size_t kst = (kt < 8) ? 2048 : 3072;
    int joff = (kt < 8) ? 0 : 512;
#pragma unroll
    for (int p = 0; p < 2; ++p){
      int jl = srow + p * 32;
      gload16(kb + (size_t)((j0 + jl - joff) * 4 + b) * kst + gsl, (void*)&sK[buf][p * 2048 + tid * 8]);
    }
#pragma unroll
    for (int p = 0; p < 2; ++p){
      int dl = srow + p * 32;
      gload16(vb2 + ((size_t)dl << 10) + j0 + gsl, (void*)&sV[buf][p * 2048 + tid * 8]);
    }
  };

  auto compute = [&](int cur, int kt){
    int j0 = kt << 6;
    f32x4 sacc[4];
#pragma unroll
    for (int jf = 0; jf < 4; ++jf) sacc[jf] = (f32x4)(0.0f);
    __builtin_amdgcn_s_setprio(1);
#pragma unroll
    for (int ks = 0; ks < 2; ++ks){
      int sl = ((ks * 4 + g) ^ (t & 7)) * 8;
#pragma unroll
      for (int jf = 0; jf < 4; ++jf){
        bf16x8 kf = *(const bf16x8*)(&sK[cur][(jf * 16 + t) * 64 + sl]);
        sacc[jf] = __builtin_amdgcn_mfma_f32_16x16x32_bf16(kf, qfrag[ks], sacc[jf], 0, 0, 0);
      }
    }
    __builtin_amdgcn_s_setprio(0);
    bool part = (j0 + 63 > i0 + 512);
    float ps[4][4];
    float tmax = -1e30f;
#pragma unroll
    for (int jf = 0; jf < 4; ++jf)
#pragma unroll
      for (int r = 0; r < 4; ++r){
        float s = sacc[jf][r] * 0.125f;
        if (part && (j0 + jf * 16 + g * 4 + r > i + 512)) s = -1e30f;
        ps[jf][r] = s;
        tmax = fmaxf(tmax, s);
      }
    tmax = fmaxf(tmax, __shfl_xor(tmax, 16));
    tmax = fmaxf(tmax, __shfl_xor(tmax, 32));
    float mnew = fmaxf(mrun, tmax);
    float sc = __expf(mrun - mnew);
    mrun = mnew;
    lrun *= sc;
    u32 pk0[2], pk1[2], pk2[2], pk3[2];
    {
      float e0, e1, e2, e3;
#define DO_JF(PK, JF) \
      e0 = __expf(ps[JF][0] - mnew); e1 = __expf(ps[JF][1] - mnew); \
      e2 = __expf(ps[JF][2] - mnew); e3 = __expf(ps[JF][3] - mnew); \
      lrun += (e0 + e1) + (e2 + e3); \
      PK[0] = pack2bf(e0, e1); PK[1] = pack2bf(e2, e3);
      DO_JF(pk0, 0) DO_JF(pk1, 1) DO_JF(pk2, 2) DO_JF(pk3, 3)
#undef DO_JF
    }
#pragma unroll
    for (int df = 0; df < 4; ++df)
#pragma unroll
      for (int r = 0; r < 4; ++r) oacc[df][r] *= sc;

    int srcA = t + 16 * ((2 * g) & 3);
    int srcB = t + 16 * ((2 * g + 1) & 3);
    bool ghi = (g >= 2);
#pragma unroll
    for (int ks = 0; ks < 2; ++ks){
      u32 w0a, w1a, w2a, w3a, w0b, w1b, w2b, w3b;
      if (ks == 0){
        w0a = __shfl((int)pk0[0], srcA); w1a = __shfl((int)pk0[1], srcA);
        w2a = __shfl((int)pk0[0], srcB); w3a = __shfl((int)pk0[1], srcB);
        w0b = __shfl((int)pk1[0], srcA); w1b = __shfl((int)pk1[1], srcA);
        w2b = __shfl((int)pk1[0], srcB); w3b = __shfl((int)pk1[1], srcB);
      } else {
        w0a = __shfl((int)pk2[0], srcA); w1a = __shfl((int)pk2[1], srcA);
        w2a = __shfl((int)pk2[0], srcB); w3a = __shfl((int)pk2[1], srcB);
        w0b = __shfl((int)pk3[0], srcA); w1b = __shfl((int)pk3[1], srcA);
        w2b = __shfl((int)pk3[0], srcB); w3b = __shfl((int)pk3[1], srcB);
      }
      Cvt c;
      c.u[0] = ghi ? w0b : w0a;
      c.u[1] = ghi ? w1b : w1a;
      c.u[2] = ghi ? w2b : w2a;
      c.u[3] = ghi ? w3b : w3a;
      bf16x8 pf = c.v;
      int sl = ((ks * 4 + g) ^ (t & 7)) * 8;
      __builtin_amdgcn_s_setprio(1);
#pragma unroll
      for (int df = 0; df < 4; ++df){
        bf16x8 vf = *(const bf16x8*)(&sV[cur][(df * 16 + t) * 64 + sl]);
        oacc[df] = __builtin_amdgcn_mfma_f32_16x16x32_bf16(vf, pf, oacc[df], 0, 0, 0);
      }
      __builtin_amdgcn_s_setprio(0);
    }
  };

  int kt1 = qt + 9;
  stageKV(0, 0);
  stageKV(1, 1);
  __syncthreads();
  for (int kt = 0; kt < kt1; kt += 2){
    if (kt + 2 < kt1) stageKV((kt + 2) & 3, kt + 2);
    if (kt + 3 < kt1) stageKV((kt + 3) & 3, kt + 3);
    compute(kt & 3, kt);
    if (kt + 1 < kt1) compute((kt + 1) & 3, kt + 1);
    __syncthreads();
  }
  lrun += __shfl_xor(lrun, 16);
  lrun += __shfl_xor(lrun, 32);
  float inv = 1.0f / lrun;

  u16* orow = attnbf + ((size_t)(i * 4 + b) << 10) + n * 64;
#pragma unroll
  for (int df = 0; df < 4; ++df){
#pragma unroll
    for (int h = 0; h < 2; ++h){
      *(u32*)(orow + df * 16 + g * 4 + 2 * h) = pack2bf(oacc[df][2 * h] * inv, oacc[df][2 * h + 1] * inv);
    }
  }
}

// ---------------- bf16 residual + (bf16 split-K partial sum) + bias + layernorm ----------------
__global__ __launch_bounds__(256) void ln_k(const u16* __restrict__ resbf, const u16* __restrict__ parts,
                                            size_t pstride, int np, const float* __restrict__ bias,
                                            const float* __restrict__ g, const float* __restrict__ bta,
                                            u16* __restrict__ hbf, float* __restrict__ fout)
{
  int row = blockIdx.x, tid = threadIdx.x;
  int d0 = tid << 2;
  size_t ro = (size_t)row << 10;
  u16x4 rv = *(const u16x4*)(resbf + ro + d0);
  f32x4 v;
#pragma unroll
  for (int j = 0; j < 4; ++j) v[j] = bf2f(rv[j]);
  if (bias){
    f32x4 bv = *(const f32x4*)(bias + d0);
#pragma unroll
    for (int j = 0; j < 4; ++j) v[j] += bv[j];
  }
  for (int p = 0; p < np; ++p){
    u16x4 pv = *(const u16x4*)(parts + p * pstride + ro + d0);
#pragma unroll
    for (int j = 0; j < 4; ++j) v[j] += bf2f(pv[j]);
  }
  float s = (v[0] + v[1]) + (v[2] + v[3]);
  float s2 = (v[0] * v[0] + v[1] * v[1]) + (v[2] * v[2] + v[3] * v[3]);
#pragma unroll
  for (int off = 32; off; off >>= 1){ s += __shfl_xor(s, off); s2 += __shfl_xor(s2, off); }
  __shared__ float ps[8];
  int wid = tid >> 6, lane = tid & 63;
  if (lane == 0){ ps[wid] = s; ps[wid + 4] = s2; }
  __syncthreads();
  s  = ps[0] + ps[1] + ps[2] + ps[3];
  s2 = ps[4] + ps[5] + ps[6] + ps[7];
  float mu = s * 0.0009765625f;
  float var = s2 * 0.0009765625f - mu * mu;
  float rstd = rsqrtf(var + 1e-5f);
  f32x4 gv = *(const f32x4*)(g + d0);
  f32x4 bt = *(const f32x4*)(bta + d0);
  f32x4 fo;
  u16x4 hb;
#pragma unroll
  for (int j = 0; j < 4; ++j){
    float tv = (v[j] - mu) * rstd * gv[j] + bt[j];
    fo[j] = tv; hb[j] = f2bf(tv);
  }
  *(u16x4*)(hbf + ro + d0) = hb;
  if (fout) *(f32x4*)(fout + ro + d0) = fo;
}

extern "C" void kernel_launch(void* const* d_in, const int* in_sizes, int n_in,
                              void* d_out, int out_size, void* d_ws, size_t ws_size,
                              hipStream_t stream)
{
  const int*   data = (const int*)  d_in[0];
  const float* mems = (const float*)d_in[1];
  const float* emb  = (const float*)d_in[2];
  const float* Wq   = (const float*)d_in[3];
  const float* Wkv  = (const float*)d_in[4];
  const float* Wo   = (const float*)d_in[5];
  const float* ln1g = (const float*)d_in[6];
  const float* ln1b = (const float*)d_in[7];
  const float* W1   = (const float*)d_in[8];
  const float* b1   = (const float*)d_in[9];
  const float* W2   = (const float*)d_in[10];
  const float* b2   = (const float*)d_in[11];
  const float* ln2g = (const float*)d_in[12];
  const float* ln2b = (const float*)d_in[13];
  float* out = (float*)d_out;

  char* ws = (char*)d_ws;
  size_t off = 0;
  auto alloc = [&](size_t bytes) -> char* {
    char* p = ws + off;
    off = (off + bytes + 255) & ~(size_t)255;
    return p;
  };

  u16*   wqkv_bf = (u16*) alloc((size_t)6 * 3072 * 1024 * 2);
  u16*   wo_bf   = (u16*) alloc((size_t)6 * 1024 * 1024 * 2);
  u16*   w1_bf   = (u16*) alloc((size_t)6 * 4096 * 1024 * 2);
  u16*   w2_bf   = (u16*) alloc((size_t)6 * 1024 * 4096 * 2);
  u16*   memsbf  = (u16*) alloc((size_t)6 * 2048 * 1024 * 2);
  u16*   kvmem   = (u16*) alloc((size_t)6 * 2048 * 2048 * 2);
  u16*   vtbf    = (u16*) alloc((size_t)6 * 64 * 64 * 1024 * 2);
  u16*   hbf     = (u16*) alloc((size_t)2048 * 1024 * 2);
  u16*   qkv     = (u16*) alloc((size_t)2048 * 3072 * 2);
  u16*   attnbf  = (u16*) alloc((size_t)2048 * 1024 * 2);
  u16*   f1bf    = (u16*) alloc((size_t)2048 * 4096 * 2);
  u16*   pbf     = (u16*) alloc((size_t)4 * 2048 * 1024 * 2);
  const size_t PS = (size_t)2048 * 1024;
  const size_t VTL = (size_t)64 * 64 * 1024;

  // ---- layer-independent preamble ----
  conv_bf16_t<<<dim3(16, 16, 6), 256, 0, stream>>>(Wq,  wqkv_bf, 1024, 1024, (size_t)3072 * 1024, 0);
  conv_bf16_t<<<dim3(32, 16, 6), 256, 0, stream>>>(Wkv, wqkv_bf, 1024, 2048, (size_t)3072 * 1024, 1024);
  conv_bf16_t<<<dim3(16, 16, 6), 256, 0, stream>>>(Wo,  wo_bf,   1024, 1024, (size_t)1024 * 1024, 0);
  conv_bf16_t<<<dim3(64, 16, 6), 256, 0, stream>>>(W1,  w1_bf,   1024, 4096, (size_t)4096 * 1024, 0);
  conv_bf16_t<<<dim3(16, 64, 6), 256, 0, stream>>>(W2,  w2_bf,   4096, 1024, (size_t)4096 * 1024, 0);
  conv_bf16<<<12288, 256, 0, stream>>>(mems, memsbf);
  embed_k<<<8192, 256, 0, stream>>>(data, emb, hbf);
  // batched mems-KV GEMM (BM=128) with fused V-transpose
  gemm_bt<128><<<dim3(16, 16, 6), 256, 0, stream>>>(memsbf, wqkv_bf + (size_t)1024 * 1024, nullptr,
      nullptr, kvmem, nullptr, 2048, 2048, 1024, 1024, 0,
      (size_t)2048 * 1024, (size_t)3072 * 1024, (size_t)2048 * 2048,
      vtbf, VTL, 0, 0);

  for (int l = 0; l < 6; ++l){
    u16* kvm_l = kvmem + (size_t)l * 2048 * 2048;
    u16* vt_l  = vtbf + (size_t)l * VTL;
    gemm_bt<64><<<dim3(24, 32), 256, 0, stream>>>(hbf, wqkv_bf + (size_t)l * 3072 * 1024, nullptr,
        nullptr, qkv, nullptr, 2048, 3072, 1024, 1024, 0, 0, 0, 0,
        vt_l, 0, 1024, 512);
    attn_mfma<<<dim3(8, 64), 256, 0, stream>>>(qkv, kvm_l, vt_l, attnbf);
    gemm_bt<64><<<dim3(8, 32, 2), 256, 0, stream>>>(attnbf, wo_bf + (size_t)l * 1024 * 1024, nullptr,
        nullptr, nullptr, pbf, 2048, 1024, 1024, 512, 0, 0, 0, 0,
        nullptr, 0, 0, 0);
    ln_k<<<2048, 256, 0, stream>>>(hbf, pbf, PS, 2, nullptr, ln1g + l * 1024, ln1b + l * 1024, hbf, nullptr);
    // W1 + bias + relu (2-phase BM=128 — reverted from 8-phase regression)
    gemm_bt<128><<<dim3(32, 16), 256, 0, stream>>>(hbf, w1_bf + (size_t)l * 4096 * 1024,
        b1 + (size_t)l * 4096, nullptr, f1bf, nullptr, 2048, 4096, 1024, 1024, 1, 0, 0, 0,
        nullptr, 0, 0, 0);
    gemm_bt<128><<<dim3(8, 16, 4), 256, 0, stream>>>(f1bf, w2_bf + (size_t)l * 4096 * 1024, nullptr,
        nullptr, nullptr, pbf, 2048, 1024, 4096, 1024, 0, 0, 0, 0,
        nullptr, 0, 0, 0);
    ln_k<<<2048, 256, 0, stream>>>(hbf, pbf, PS, 4, b2 + l * 1024, ln2g + l * 1024, ln2b + l * 1024,
                                   hbf, (l == 5) ? out : nullptr);
  }
}